// Round 3
// baseline (1311.760 us; speedup 1.0000x reference)
//
#include <hip/hip_runtime.h>

// Problem constants: B=64, S=512, E=512, H=512, V=32000, T=2, L=1
// Output depends ONLY on batch sample 63 (lstm_out[-1] == last batch element).

typedef float f32x4 __attribute__((ext_vector_type(4)));
typedef unsigned long long u64;

#define NB 32   // persistent blocks for the recurrence (16 h-values each)

// ---------------------------------------------------------------------------
// Kernel 1: xg[t][g] = sum_e emb[sent[63][t]][e] * W_ih[g][e] + b_ih[g]+b_hh[g]
// M=512 (t), N=2048 (g), K=512. Both operands K-major (NT GEMM). (unchanged)
// ---------------------------------------------------------------------------
__global__ __launch_bounds__(256) void xg_gemm_k(
    const int* __restrict__ sent, const float* __restrict__ emb,
    const float* __restrict__ W_ih, const float* __restrict__ b_ih,
    const float* __restrict__ b_hh, float* __restrict__ xg)
{
    __shared__ float As[16][65];   // [k][m]
    __shared__ float Bs[16][65];   // [k][n]
    __shared__ int aidx[64];
    const int tid = threadIdx.x;
    const int t0 = blockIdx.x * 64;
    const int n0 = blockIdx.y * 64;
    if (tid < 64) aidx[tid] = sent[63 * 512 + t0 + tid];
    __syncthreads();

    const int kk = tid & 15;   // k within tile
    const int mm = tid >> 4;   // 0..15
    const int tx = tid & 15, ty = tid >> 4;
    float acc[4][4] = {};

    for (int kb = 0; kb < 512; kb += 16) {
        #pragma unroll
        for (int j = 0; j < 4; j++) {
            int m = mm + j * 16;
            As[kk][m] = emb[(size_t)aidx[m] * 512 + kb + kk];
            Bs[kk][m] = W_ih[(size_t)(n0 + m) * 512 + kb + kk];
        }
        __syncthreads();
        #pragma unroll
        for (int k = 0; k < 16; k++) {
            float a[4], bv[4];
            #pragma unroll
            for (int i = 0; i < 4; i++) a[i] = As[k][ty * 4 + i];
            #pragma unroll
            for (int j = 0; j < 4; j++) bv[j] = Bs[k][tx * 4 + j];
            #pragma unroll
            for (int i = 0; i < 4; i++)
                #pragma unroll
                for (int j = 0; j < 4; j++)
                    acc[i][j] += a[i] * bv[j];
        }
        __syncthreads();
    }

    #pragma unroll
    for (int i = 0; i < 4; i++) {
        int t = t0 + ty * 4 + i;
        #pragma unroll
        for (int j = 0; j < 4; j++) {
            int col = n0 + tx * 4 + j;
            xg[(size_t)t * 2048 + col] = acc[i][j] + b_ih[col] + b_hh[col];
        }
    }
}

// ---------------------------------------------------------------------------
// Kernel 2: persistent batch-1 LSTM recurrence, 512 steps, 32 blocks x 256.
// Block b owns h-indices [b*16, b*16+16). Thread (j=tid>>4, cg=tid&15) owns
// the 4 gate rows {q*512 + b*16 + j}, columns [cg*32, cg*32+32).
//
// Handoff (PROVEN protocol, unchanged): h values travel as tagged 64-bit
// slots  slot = (u64)(t+1)<<32 | float_bits(h_t), stored with relaxed
// agent-scope 8B atomic stores. Readers poll the slots themselves — the
// poll IS the data read. Two slot arrays ping-pong by step parity; the
// protocol is dependency-ordered race-free without fences.
//
// CHANGES vs 838us baseline:
//  * NB 64->32: halves producer-straggler spread and LLC poll contention.
//  * Weights (128 floats/thread) pinned ONCE BEFORE the loop with an empty
//    "+v" asm: values become asm outputs -> remat from L2 illegal; allocator
//    unconstrained inside the loop (round-2's in-loop pin caused scratch
//    shuttling; VGPR_Count stayed 60 -> weights were L2-streamed each step,
//    ~1100cy/step).
//  * Poll is 2-deep pipelined on ADJACENT slots (2*tid, 2*tid+1): next load
//    pair issued before checking current -> discovery ~0.5 round trips.
//  * One barrier per step; hb parity double-buffered; chunk-padded LDS
//    (stride 36 words) -> <=2-way read aliasing (free), <=4-way on the
//    single paired write (negligible).
// ---------------------------------------------------------------------------
__global__ __launch_bounds__(256, 1) void lstm_seq_k(
    const float* __restrict__ h0, const float* __restrict__ c0,
    const float* __restrict__ W_hh, const float* __restrict__ xg,
    float* __restrict__ hs,
    u64* __restrict__ sA, u64* __restrict__ sB)
{
    __shared__ float hb[2][16 * 36];   // 16 chunks of 32 floats, stride 36

    const int tid = threadIdx.x;
    const int b = blockIdx.x;
    const int cg = tid & 15;   // column group: 32 cols each
    const int j  = tid >> 4;   // h index within block: 0..15

    // Gate rows for this thread's j: torch order i,f,g,o = q 0..3.
    int grow[4];
    #pragma unroll
    for (int r = 0; r < 4; ++r)
        grow[r] = r * 512 + b * 16 + j;

    // Weight slice: 4 rows x 32 cols = 128 floats/thread, loaded ONCE.
    f32x4 w[4][8];
    #pragma unroll
    for (int r = 0; r < 4; ++r)
        #pragma unroll
        for (int cq = 0; cq < 8; ++cq)
            w[r][cq] = *(const f32x4*)&W_hh[(size_t)grow[r] * 512 + cg * 32 + cq * 4];

    // Pin ONCE, before the loop: weights become asm outputs -> the compiler
    // cannot re-load them from global inside the loop; no per-iteration asm.
    #pragma unroll
    for (int r = 0; r < 4; ++r)
        asm volatile("" : "+v"(w[r][0]), "+v"(w[r][1]), "+v"(w[r][2]),
                          "+v"(w[r][3]), "+v"(w[r][4]), "+v"(w[r][5]),
                          "+v"(w[r][6]), "+v"(w[r][7]));

    // c state: used by the cg==0 lane of each j-group.
    float creg = c0[63 * 512 + b * 16 + j];

    for (int t = 0; t < 512; ++t) {
        const int p = t & 1;

        // Prefetch xg for this step (independent of h -> overlaps the poll).
        float xgp[4];
        if (cg == 0) {
            #pragma unroll
            for (int r = 0; r < 4; ++r)
                xgp[r] = xg[(size_t)t * 2048 + grow[r]];
        }

        if (t == 0) {
            const int e0 = 2 * tid;
            hb[p][(e0 >> 5) * 36 + (e0 & 31)]     = h0[63 * 512 + e0];
            hb[p][(e0 >> 5) * 36 + (e0 & 31) + 1] = h0[63 * 512 + e0 + 1];
        } else {
            // Poll tagged slots of step t-1 (tag == t), buffer (t-1)&1,
            // 2-deep pipelined: issue next pair before checking current.
            u64* src = ((t - 1) & 1) ? sB : sA;
            u64* p0 = &src[2 * tid];
            u64* p1 = &src[2 * tid + 1];
            const unsigned expt = (unsigned)t;
            u64 v0 = __hip_atomic_load(p0, __ATOMIC_RELAXED, __HIP_MEMORY_SCOPE_AGENT);
            u64 v1 = __hip_atomic_load(p1, __ATOMIC_RELAXED, __HIP_MEMORY_SCOPE_AGENT);
            for (;;) {
                u64 n0 = __hip_atomic_load(p0, __ATOMIC_RELAXED, __HIP_MEMORY_SCOPE_AGENT);
                u64 n1 = __hip_atomic_load(p1, __ATOMIC_RELAXED, __HIP_MEMORY_SCOPE_AGENT);
                if ((unsigned)(v0 >> 32) == expt &&
                    (unsigned)(v1 >> 32) == expt) break;
                v0 = n0; v1 = n1;
            }
            const int e0 = 2 * tid;
            hb[p][(e0 >> 5) * 36 + (e0 & 31)]     = __uint_as_float((unsigned)v0);
            hb[p][(e0 >> 5) * 36 + (e0 & 31) + 1] = __uint_as_float((unsigned)v1);
        }
        __syncthreads();   // the ONLY barrier per step: hb[p] complete

        // 4 gate rows x 32 cols of FMA per thread; chunk cg, <=2-way banks.
        f32x4 hv[8];
        #pragma unroll
        for (int cq = 0; cq < 8; ++cq)
            hv[cq] = *(const f32x4*)&hb[p][cg * 36 + cq * 4];

        float acc[4];
        #pragma unroll
        for (int r = 0; r < 4; ++r) {
            float s = 0.f;
            #pragma unroll
            for (int cq = 0; cq < 8; ++cq) {
                s += w[r][cq].x * hv[cq].x;
                s += w[r][cq].y * hv[cq].y;
                s += w[r][cq].z * hv[cq].z;
                s += w[r][cq].w * hv[cq].w;
            }
            acc[r] = s;
        }

        // Reduce over the 16 column-group lanes (masks <=8 stay in group).
        #pragma unroll
        for (int r = 0; r < 4; ++r) {
            #pragma unroll
            for (int m = 8; m >= 1; m >>= 1)
                acc[r] += __shfl_xor(acc[r], m, 64);
        }

        // Gate tail inline on lane cg==0 of each j-group (16 lanes, 4/wave).
        if (cg == 0) {
            float gi = acc[0] + xgp[0];
            float gf = acc[1] + xgp[1];
            float gc = acc[2] + xgp[2];
            float go = acc[3] + xgp[3];
            float ii = 1.f / (1.f + __expf(-gi));
            float ff = 1.f / (1.f + __expf(-gf));
            float cc = 1.f - 2.f / (__expf(2.f * gc) + 1.f);   // tanh
            float oo = 1.f / (1.f + __expf(-go));
            float cn = ff * creg + ii * cc;
            creg = cn;
            float th = 1.f - 2.f / (__expf(2.f * cn) + 1.f);   // tanh
            float hval = oo * th;

            // History for the final linear (plain store; kernel-boundary
            // release makes it visible to kernel 3).
            hs[(size_t)t * 512 + b * 16 + j] = hval;

            // Tagged slot: one 8B relaxed agent atomic store.
            u64* dst = (t & 1) ? sB : sA;
            u64 pv = ((u64)(unsigned)(t + 1) << 32) |
                     (u64)__float_as_uint(hval);
            __hip_atomic_store(&dst[b * 16 + j], pv,
                               __ATOMIC_RELAXED, __HIP_MEMORY_SCOPE_AGENT);
        }
        // NO fence, NO flag store, NO trailing barrier (hb double-buffered).
    }
}

// ---------------------------------------------------------------------------
// Kernel 3: out[s][u] = hs[s] . W_lin[u] + b_lin[u], S=512, T=2. (unchanged)
// ---------------------------------------------------------------------------
__global__ __launch_bounds__(256) void final_linear_k(
    const float* __restrict__ hs, const float* __restrict__ W_lin,
    const float* __restrict__ b_lin, float* __restrict__ out)
{
    const int tid = threadIdx.x;
    const int wave = tid >> 6;
    const int lane = tid & 63;
    const int s = blockIdx.x * 4 + wave;
    const float* h = hs + (size_t)s * 512;
    float a0 = 0.f, a1 = 0.f;
    #pragma unroll
    for (int k0 = 0; k0 < 512; k0 += 64) {
        float hv = h[k0 + lane];
        a0 += hv * W_lin[k0 + lane];
        a1 += hv * W_lin[512 + k0 + lane];
    }
    #pragma unroll
    for (int m = 32; m >= 1; m >>= 1) {
        a0 += __shfl_xor(a0, m, 64);
        a1 += __shfl_xor(a1, m, 64);
    }
    if (lane == 0) {
        out[s * 2]     = a0 + b_lin[0];
        out[s * 2 + 1] = a1 + b_lin[1];
    }
}

// ---------------------------------------------------------------------------
extern "C" void kernel_launch(void* const* d_in, const int* in_sizes, int n_in,
                              void* d_out, int out_size, void* d_ws, size_t ws_size,
                              hipStream_t stream)
{
    const int*   sent  = (const int*)d_in[0];     // [64,512] int32
    const float* h0    = (const float*)d_in[1];   // [1,64,512]
    const float* c0    = (const float*)d_in[2];   // [1,64,512]
    const float* emb   = (const float*)d_in[3];   // [32000,512]
    const float* W_ih  = (const float*)d_in[4];   // [2048,512]
    const float* W_hh  = (const float*)d_in[5];   // [2048,512]
    const float* b_ih  = (const float*)d_in[6];   // [2048]
    const float* b_hh  = (const float*)d_in[7];   // [2048]
    const float* W_lin = (const float*)d_in[8];   // [2,512]
    const float* b_lin = (const float*)d_in[9];   // [2]
    float* out = (float*)d_out;                   // [512,2]

    char* ws = (char*)d_ws;
    float* xg = (float*)ws;                                   // 4 MB: [512,2048]
    float* hs = (float*)(ws + 4 * 1024 * 1024);               // 1 MB: [512,512]
    u64* sA = (u64*)(ws + 5 * 1024 * 1024);                   // 4 KB
    u64* sB = (u64*)(ws + 5 * 1024 * 1024 + 4096);            // 4 KB

    // Clear slot tags (0 != any expected tag 1..512).
    hipMemsetAsync(sA, 0, 2 * 4096, stream);

    dim3 g1(8, 32);
    xg_gemm_k<<<g1, 256, 0, stream>>>(sent, emb, W_ih, b_ih, b_hh, xg);
    lstm_seq_k<<<NB, 256, 0, stream>>>(h0, c0, W_hh, xg, hs, sA, sB);
    final_linear_k<<<128, 256, 0, stream>>>(hs, W_lin, b_lin, out);
}

// Round 4
// 1222.916 us; speedup vs baseline: 1.0726x; 1.0726x over previous
//
#include <hip/hip_runtime.h>

// Problem constants: B=64, S=512, E=512, H=512, V=32000, T=2, L=1
// Output depends ONLY on batch sample 63 (lstm_out[-1] == last batch element).

typedef float f32x4 __attribute__((ext_vector_type(4)));
typedef unsigned long long u64;

#define NB 64   // persistent blocks for the recurrence

// LDS h-buffer swizzle: 32 groups of 16 floats, padded to stride 20 words
// (80 B = 5 banks*16B) -> float4 reads stay 16B-aligned, 16-way conflict -> 4-way.
#define HIDX(e) ((((e) >> 4) * 20) + ((e) & 15))

// Explicit weight-load: ONE guaranteed issue point per step. Volatile asm
// cannot be sunk to the use site, so all 16 dwordx4 loads go out back-to-back
// at the top of the iteration and their ~200-400cy L2 latency hides under the
// slot-poll wait (which the compiler fences with its own vmcnt(0) anyway).
#define WLOAD(dst, ptr, off)                                       \
    asm volatile("global_load_dwordx4 %0, %1, off offset:" #off    \
                 : "=v"(dst) : "v"(ptr))
#define WROW(r)                                                    \
    WLOAD(wv[r][0], wp##r, 0);  WLOAD(wv[r][1], wp##r, 16);        \
    WLOAD(wv[r][2], wp##r, 32); WLOAD(wv[r][3], wp##r, 48)

// ---------------------------------------------------------------------------
// Kernel 1: xg[t][g] = sum_e emb[sent[63][t]][e] * W_ih[g][e] + b_ih[g]+b_hh[g]
// M=512 (t), N=2048 (g), K=512. Both operands K-major (NT GEMM). (unchanged)
// ---------------------------------------------------------------------------
__global__ __launch_bounds__(256) void xg_gemm_k(
    const int* __restrict__ sent, const float* __restrict__ emb,
    const float* __restrict__ W_ih, const float* __restrict__ b_ih,
    const float* __restrict__ b_hh, float* __restrict__ xg)
{
    __shared__ float As[16][65];   // [k][m]
    __shared__ float Bs[16][65];   // [k][n]
    __shared__ int aidx[64];
    const int tid = threadIdx.x;
    const int t0 = blockIdx.x * 64;
    const int n0 = blockIdx.y * 64;
    if (tid < 64) aidx[tid] = sent[63 * 512 + t0 + tid];
    __syncthreads();

    const int kk = tid & 15;   // k within tile
    const int mm = tid >> 4;   // 0..15
    const int tx = tid & 15, ty = tid >> 4;
    float acc[4][4] = {};

    for (int kb = 0; kb < 512; kb += 16) {
        #pragma unroll
        for (int j = 0; j < 4; j++) {
            int m = mm + j * 16;
            As[kk][m] = emb[(size_t)aidx[m] * 512 + kb + kk];
            Bs[kk][m] = W_ih[(size_t)(n0 + m) * 512 + kb + kk];
        }
        __syncthreads();
        #pragma unroll
        for (int k = 0; k < 16; k++) {
            float a[4], bv[4];
            #pragma unroll
            for (int i = 0; i < 4; i++) a[i] = As[k][ty * 4 + i];
            #pragma unroll
            for (int j = 0; j < 4; j++) bv[j] = Bs[k][tx * 4 + j];
            #pragma unroll
            for (int i = 0; i < 4; i++)
                #pragma unroll
                for (int j = 0; j < 4; j++)
                    acc[i][j] += a[i] * bv[j];
        }
        __syncthreads();
    }

    #pragma unroll
    for (int i = 0; i < 4; i++) {
        int t = t0 + ty * 4 + i;
        #pragma unroll
        for (int j = 0; j < 4; j++) {
            int col = n0 + tx * 4 + j;
            xg[(size_t)t * 2048 + col] = acc[i][j] + b_ih[col] + b_hh[col];
        }
    }
}

// ---------------------------------------------------------------------------
// Kernel 2: persistent batch-1 LSTM recurrence, 512 steps, 64 blocks x 256.
// Block b owns h-indices [b*8, b*8+8) -> 32 gate rows {q*512 + b*8 + j}.
//
// EXACT round-0 structure (838us, proven): tagged 64-bit slots
//   slot = (u64)(t+1) << 32 | float_bits(h_t)
// relaxed agent-scope 8B atomic stores, readers poll the slots themselves,
// two arrays ping-pong by parity, no fences. Two barriers, gacc LDS, gate
// tail on tid<8.
//
// ONE change: weights are streamed per-step via explicit volatile-asm
// global_load_dwordx4 issued at the TOP of each iteration, so the ~1100cy
// L2 stream (measured: NB 64->32 doubled the stream and added ~900cy/step)
// overlaps the slot-poll wait instead of serializing after the barrier.
// s_waitcnt vmcnt(0) + sched_barrier(0) before the FMA phase (rule: compiler
// may hoist reg-only FMAs past an inline-asm waitcnt).
// ---------------------------------------------------------------------------
__global__ __launch_bounds__(256, 1) void lstm_seq_k(
    const float* __restrict__ h0, const float* __restrict__ c0,
    const float* __restrict__ W_hh, const float* __restrict__ xg,
    float* __restrict__ hs,
    u64* __restrict__ sA, u64* __restrict__ sB)
{
    __shared__ float hbuf[32 * 20];
    __shared__ float gacc[32];
    __shared__ float cbuf[8];

    const int tid = threadIdx.x;
    const int b = blockIdx.x;
    const int cg = tid & 31;   // column group: 16 cols each
    const int rg = tid >> 5;   // row group: 4 rows each, 8 groups = 32 rows

    // Global gate-row indices for this thread's 4 rows.
    const int rl0 = rg * 4;
    const int grow0 = ((rl0 + 0) >> 3) * 512 + b * 8 + ((rl0 + 0) & 7);
    const int grow1 = ((rl0 + 1) >> 3) * 512 + b * 8 + ((rl0 + 1) & 7);
    const int grow2 = ((rl0 + 2) >> 3) * 512 + b * 8 + ((rl0 + 2) & 7);
    const int grow3 = ((rl0 + 3) >> 3) * 512 + b * 8 + ((rl0 + 3) & 7);

    // Loop-invariant row base pointers for the streamed weight loads.
    const float* wp0 = &W_hh[(size_t)grow0 * 512 + cg * 16];
    const float* wp1 = &W_hh[(size_t)grow1 * 512 + cg * 16];
    const float* wp2 = &W_hh[(size_t)grow2 * 512 + cg * 16];
    const float* wp3 = &W_hh[(size_t)grow3 * 512 + cg * 16];

    if (tid < 8) cbuf[tid] = c0[63 * 512 + b * 8 + tid];
    __syncthreads();

    for (int t = 0; t < 512; t++) {
        // Issue this step's 16 weight loads NOW (h-independent): their L2
        // latency hides under the slot poll below.
        f32x4 wv[4][4];
        WROW(0); WROW(1); WROW(2); WROW(3);

        // Prefetch xg for this step (also independent of h).
        float xgp[4];
        if (cg == 0) {
            xgp[0] = xg[(size_t)t * 2048 + grow0];
            xgp[1] = xg[(size_t)t * 2048 + grow1];
            xgp[2] = xg[(size_t)t * 2048 + grow2];
            xgp[3] = xg[(size_t)t * 2048 + grow3];
        }

        if (t == 0) {
            hbuf[HIDX(tid)]       = h0[63 * 512 + tid];
            hbuf[HIDX(tid + 256)] = h0[63 * 512 + tid + 256];
        } else {
            // Poll tagged slots of step t-1 (tag == t) in buffer (t-1)&1.
            u64* src = ((t - 1) & 1) ? sB : sA;
            u64* p0 = &src[tid];
            u64* p1 = &src[tid + 256];
            const unsigned int expt = (unsigned int)t;
            u64 v0, v1;
            for (;;) {
                v0 = __hip_atomic_load(p0, __ATOMIC_RELAXED, __HIP_MEMORY_SCOPE_AGENT);
                v1 = __hip_atomic_load(p1, __ATOMIC_RELAXED, __HIP_MEMORY_SCOPE_AGENT);
                if ((unsigned int)(v0 >> 32) == expt &&
                    (unsigned int)(v1 >> 32) == expt) break;
            }
            hbuf[HIDX(tid)]       = __uint_as_float((unsigned int)v0);
            hbuf[HIDX(tid + 256)] = __uint_as_float((unsigned int)v1);
        }
        __syncthreads();

        // h fragment from LDS.
        f32x4 hv[4];
        #pragma unroll
        for (int cq = 0; cq < 4; cq++)
            hv[cq] = *(const f32x4*)&hbuf[cg * 20 + cq * 4];

        // Drain the weight loads (redundant after a poll, needed for t==0);
        // sched_barrier stops the FMAs being hoisted above it.
        asm volatile("s_waitcnt vmcnt(0)");
        __builtin_amdgcn_sched_barrier(0);

        // 4 rows x 16 cols of FMA per thread.
        float acc[4];
        #pragma unroll
        for (int r = 0; r < 4; r++) {
            float s = 0.f;
            #pragma unroll
            for (int cq = 0; cq < 4; cq++) {
                s += wv[r][cq].x * hv[cq].x;
                s += wv[r][cq].y * hv[cq].y;
                s += wv[r][cq].z * hv[cq].z;
                s += wv[r][cq].w * hv[cq].w;
            }
            acc[r] = s;
        }

        // Reduce over the 32 column-group lanes (xor masks <=16 stay in half-wave).
        #pragma unroll
        for (int r = 0; r < 4; r++) {
            #pragma unroll
            for (int m = 16; m >= 1; m >>= 1)
                acc[r] += __shfl_xor(acc[r], m, 64);
        }
        if (cg == 0) {
            gacc[rg * 4 + 0] = acc[0] + xgp[0];
            gacc[rg * 4 + 1] = acc[1] + xgp[1];
            gacc[rg * 4 + 2] = acc[2] + xgp[2];
            gacc[rg * 4 + 3] = acc[3] + xgp[3];
        }
        __syncthreads();

        // Gate tail on lanes 0..7 (wave 0). Torch order: i, f, g, o.
        if (tid < 8) {
            float gi = gacc[tid];
            float gf = gacc[8 + tid];
            float gc = gacc[16 + tid];
            float go = gacc[24 + tid];
            float ii = 1.f / (1.f + __expf(-gi));
            float ff = 1.f / (1.f + __expf(-gf));
            float cc = 1.f - 2.f / (__expf(2.f * gc) + 1.f);   // tanh
            float oo = 1.f / (1.f + __expf(-go));
            float cn = ff * cbuf[tid] + ii * cc;
            cbuf[tid] = cn;
            float th = 1.f - 2.f / (__expf(2.f * cn) + 1.f);   // tanh
            float hval = oo * th;

            // History for the final linear (plain store).
            hs[(size_t)t * 512 + b * 8 + tid] = hval;

            // Tagged slot: one 8B relaxed agent atomic store -> LLC.
            u64* dst = (t & 1) ? sB : sA;
            u64 pv =
                ((u64)(unsigned int)(t + 1) << 32) |
                (u64)__float_as_uint(hval);
            __hip_atomic_store(&dst[b * 8 + tid], pv,
                               __ATOMIC_RELAXED, __HIP_MEMORY_SCOPE_AGENT);
        }
        // NO __threadfence, NO flag store.
    }
}

// ---------------------------------------------------------------------------
// Kernel 3: out[s][u] = hs[s] . W_lin[u] + b_lin[u], S=512, T=2. (unchanged)
// ---------------------------------------------------------------------------
__global__ __launch_bounds__(256) void final_linear_k(
    const float* __restrict__ hs, const float* __restrict__ W_lin,
    const float* __restrict__ b_lin, float* __restrict__ out)
{
    const int tid = threadIdx.x;
    const int wave = tid >> 6;
    const int lane = tid & 63;
    const int s = blockIdx.x * 4 + wave;
    const float* h = hs + (size_t)s * 512;
    float a0 = 0.f, a1 = 0.f;
    #pragma unroll
    for (int k0 = 0; k0 < 512; k0 += 64) {
        float hv = h[k0 + lane];
        a0 += hv * W_lin[k0 + lane];
        a1 += hv * W_lin[512 + k0 + lane];
    }
    #pragma unroll
    for (int m = 32; m >= 1; m >>= 1) {
        a0 += __shfl_xor(a0, m, 64);
        a1 += __shfl_xor(a1, m, 64);
    }
    if (lane == 0) {
        out[s * 2]     = a0 + b_lin[0];
        out[s * 2 + 1] = a1 + b_lin[1];
    }
}

// ---------------------------------------------------------------------------
extern "C" void kernel_launch(void* const* d_in, const int* in_sizes, int n_in,
                              void* d_out, int out_size, void* d_ws, size_t ws_size,
                              hipStream_t stream)
{
    const int*   sent  = (const int*)d_in[0];     // [64,512] int32
    const float* h0    = (const float*)d_in[1];   // [1,64,512]
    const float* c0    = (const float*)d_in[2];   // [1,64,512]
    const float* emb   = (const float*)d_in[3];   // [32000,512]
    const float* W_ih  = (const float*)d_in[4];   // [2048,512]
    const float* W_hh  = (const float*)d_in[5];   // [2048,512]
    const float* b_ih  = (const float*)d_in[6];   // [2048]
    const float* b_hh  = (const float*)d_in[7];   // [2048]
    const float* W_lin = (const float*)d_in[8];   // [2,512]
    const float* b_lin = (const float*)d_in[9];   // [2]
    float* out = (float*)d_out;                   // [512,2]

    char* ws = (char*)d_ws;
    float* xg = (float*)ws;                                   // 4 MB: [512,2048]
    float* hs = (float*)(ws + 4 * 1024 * 1024);               // 1 MB: [512,512]
    u64* sA = (u64*)(ws + 5 * 1024 * 1024);                   // 4 KB
    u64* sB = (u64*)(ws + 5 * 1024 * 1024 + 4096);            // 4 KB

    // Clear slot tags (0 != any expected tag 1..512).
    hipMemsetAsync(sA, 0, 2 * 4096, stream);

    dim3 g1(8, 32);
    xg_gemm_k<<<g1, 256, 0, stream>>>(sent, emb, W_ih, b_ih, b_hh, xg);
    lstm_seq_k<<<NB, 256, 0, stream>>>(h0, c0, W_hh, xg, hs, sA, sB);
    final_linear_k<<<128, 256, 0, stream>>>(hs, W_lin, b_lin, out);
}